// Round 2
// baseline (24.342 us; speedup 1.0000x reference)
//
#include <hip/hip_runtime.h>
#include <cmath>

#define NMAX   8
#define NM     25      // (LMAX+1)^2
#define NSPEC  3
#define NPAIR  6
#define NTRIU  36
#define NATOM  512
#define JCHUNK 256
#define NOUT   1080    // NPAIR * 5 * NTRIU

struct Params {
    float W[NMAX * NMAX];   // W_ORTHO (symmetric)
    float invnorm[NMAX];    // 1 / norm_factor[alpha]
    float ycoef[NM];        // sph-harm coefficients * 4*pi
    float lscale[5];        // pi*sqrt(8/(2l+1))
    float pairf[NPAIR];     // sqrt(2) for unlike species pairs
};

__device__ const int TRIU_N[NTRIU] = {0,0,0,0,0,0,0,0, 1,1,1,1,1,1,1, 2,2,2,2,2,2,
                                      3,3,3,3,3, 4,4,4,4, 5,5,5, 6,6, 7};
__device__ const int TRIU_P[NTRIU] = {0,1,2,3,4,5,6,7, 1,2,3,4,5,6,7, 2,3,4,5,6,7,
                                      3,4,5,6,7, 4,5,6,7, 5,6,7, 6,7, 7};
__device__ const int PAIR_S1[NPAIR] = {0,0,0,1,1,2};
__device__ const int PAIR_S2[NPAIR] = {0,1,2,1,2,2};

__global__ __launch_bounds__(256)
void soap_kernel(const float* __restrict__ pos, const int* __restrict__ Z,
                 float* __restrict__ out, Params prm) {
    __shared__ float g_lds[JCHUNK * NMAX];
    __shared__ float y_lds[JCHUNK * NM];
    __shared__ int   s_lds[JCHUNK];
    __shared__ int   cnt;
    __shared__ float c_lds[NSPEC * NMAX * NM];

    const int tid  = threadIdx.x;
    const int site = blockIdx.x;        // b*NATOM + i
    const int b    = site >> 9;         // NATOM = 512

    const float xi = pos[site * 3 + 0];
    const float yi = pos[site * 3 + 1];
    const float zi = pos[site * 3 + 2];

    // this thread owns fixed (n,m); accumulates c for the 3 species in regs
    const int  own_n = tid & 7;
    const int  own_m = tid >> 3;
    const bool owner = (tid < NMAX * NM);   // 200 threads
    float c0 = 0.f, c1 = 0.f, c2 = 0.f;

    for (int chunk = 0; chunk < NATOM; chunk += JCHUNK) {
        if (tid == 0) cnt = 0;
        __syncthreads();

        // ---- Phase A: test one neighbor, compact within-cutoff into LDS ----
        {
            const int ja = (b << 9) + chunk + tid;
            const float dx = xi - pos[ja * 3 + 0];
            const float dy = yi - pos[ja * 3 + 1];
            const float dz = zi - pos[ja * 3 + 2];
            const float d2 = dx * dx + dy * dy + dz * dz;
            if (d2 < 25.0f) {
                const int slot = atomicAdd(&cnt, 1);
                const float dist = sqrtf(d2);
                const float inv  = dist > 0.f ? 1.f / dist : 0.f;
                const float x = dx * inv, y = dy * inv, z = dz * inv;
                const float x2 = x * x, y2 = y * y, z2 = z * z;
                const float r2 = x2 + y2 + z2;

                float Yv[NM];
                Yv[0]  = prm.ycoef[0];
                Yv[1]  = prm.ycoef[1]  * y;
                Yv[2]  = prm.ycoef[2]  * z;
                Yv[3]  = prm.ycoef[3]  * x;
                Yv[4]  = prm.ycoef[4]  * x * y;
                Yv[5]  = prm.ycoef[5]  * y * z;
                Yv[6]  = prm.ycoef[6]  * (3.f * z2 - r2);
                Yv[7]  = prm.ycoef[7]  * x * z;
                Yv[8]  = prm.ycoef[8]  * (x2 - y2);
                Yv[9]  = prm.ycoef[9]  * y * (3.f * x2 - y2);
                Yv[10] = prm.ycoef[10] * x * y * z;
                Yv[11] = prm.ycoef[11] * y * (5.f * z2 - r2);
                Yv[12] = prm.ycoef[12] * z * (5.f * z2 - 3.f * r2);
                Yv[13] = prm.ycoef[13] * x * (5.f * z2 - r2);
                Yv[14] = prm.ycoef[14] * z * (x2 - y2);
                Yv[15] = prm.ycoef[15] * x * (x2 - 3.f * y2);
                Yv[16] = prm.ycoef[16] * x * y * (x2 - y2);
                Yv[17] = prm.ycoef[17] * y * z * (3.f * x2 - y2);
                Yv[18] = prm.ycoef[18] * x * y * (7.f * z2 - r2);
                Yv[19] = prm.ycoef[19] * y * z * (7.f * z2 - 3.f * r2);
                Yv[20] = prm.ycoef[20] * (35.f * z2 * z2 - 30.f * z2 * r2 + 3.f * r2 * r2);
                Yv[21] = prm.ycoef[21] * x * z * (7.f * z2 - 3.f * r2);
                Yv[22] = prm.ycoef[22] * (x2 - y2) * (7.f * z2 - r2);
                Yv[23] = prm.ycoef[23] * x * z * (x2 - 3.f * y2);
                Yv[24] = prm.ycoef[24] * (x2 * x2 - 6.f * x2 * y2 + y2 * y2);
#pragma unroll
                for (int m = 0; m < NM; ++m) y_lds[slot * NM + m] = Yv[m];

                // radial basis: dr^(a+3) / norm, a = 0..7
                const float dr = 5.f - dist;
                float bas[NMAX];
                float drp = dr * dr * dr;
#pragma unroll
                for (int a = 0; a < NMAX; ++a) { bas[a] = drp * prm.invnorm[a]; drp *= dr; }
#pragma unroll
                for (int n = 0; n < NMAX; ++n) {
                    float acc = 0.f;
#pragma unroll
                    for (int a = 0; a < NMAX; ++a) acc += bas[a] * prm.W[n * NMAX + a];
                    g_lds[slot * NMAX + n] = acc;
                }
                const int zz = Z[ja];
                s_lds[slot] = (zz == 1) ? 0 : (zz == 6) ? 1 : 2;
            }
        }
        __syncthreads();

        // ---- Phase B: accumulate c[s][own_n][own_m] over compacted slots ----
        const int M = cnt;
        if (owner) {
            for (int sl = 0; sl < M; ++sl) {
                const float g  = g_lds[sl * NMAX + own_n];
                const float yv = y_lds[sl * NM + own_m];
                const int   ss = s_lds[sl];
                const float prod = g * yv;
                c0 += (ss == 0) ? prod : 0.f;
                c1 += (ss == 1) ? prod : 0.f;
                c2 += (ss == 2) ? prod : 0.f;
            }
        }
        __syncthreads();
    }

    if (owner) {
        c_lds[0 * 200 + own_n * NM + own_m] = c0;
        c_lds[1 * 200 + own_n * NM + own_m] = c1;
        c_lds[2 * 200 + own_n * NM + own_m] = c2;
    }
    __syncthreads();

    // ---- Phase C: power spectrum outputs ----
    for (int o = tid; o < NOUT; o += 256) {
        const int q   = o / 180;
        const int rem = o - q * 180;
        const int l   = rem / 36;
        const int t   = rem - l * 36;
        const int n  = TRIU_N[t], p = TRIU_P[t];
        const int s1 = PAIR_S1[q], s2 = PAIR_S2[q];
        const int m0 = l * l;
        const int mc = 2 * l + 1;
        const float* ca = &c_lds[s1 * 200 + n * NM + m0];
        const float* cb = &c_lds[s2 * 200 + p * NM + m0];
        float sum = 0.f;
        for (int k = 0; k < mc; ++k) sum += ca[k] * cb[k];
        float scale = prm.pairf[q] * prm.lscale[l];
        if (n != p) scale *= 1.41421356237309515f;
        out[site * NOUT + o] = sum * scale;
    }
}

extern "C" void kernel_launch(void* const* d_in, const int* in_sizes, int n_in,
                              void* d_out, int out_size, void* d_ws, size_t ws_size,
                              hipStream_t stream) {
    const float* pos = (const float*)d_in[0];
    const int*   Z   = (const int*)d_in[1];
    float*       out = (float*)d_out;
    const int nsite  = in_sizes[1];   // B*N = 2048

    Params prm;

    // ---- W_ORTHO = S^(-1/2) via cyclic Jacobi (double precision, host) ----
    double A[8][8], V[8][8];
    for (int i = 0; i < 8; ++i)
        for (int j = 0; j < 8; ++j) {
            const double ai = i + 1.0, aj = j + 1.0;
            A[i][j] = sqrt((5.0 + 2.0 * ai) * (5.0 + 2.0 * aj)) / (5.0 + ai + aj);
            V[i][j] = (i == j) ? 1.0 : 0.0;
        }
    for (int sweep = 0; sweep < 30; ++sweep) {
        for (int p = 0; p < 8; ++p)
            for (int q = p + 1; q < 8; ++q) {
                const double apq = A[p][q];
                if (fabs(apq) < 1e-300) continue;
                // zeroing condition for A <- J^T A J with J=[[c,s],[-s,c]]:
                // tan(2*phi) = 2*apq / (aqq - app)
                const double phi = 0.5 * atan2(2.0 * apq, A[q][q] - A[p][p]);
                const double c = cos(phi), s = sin(phi);
                for (int k = 0; k < 8; ++k) {   // A <- A * J
                    const double akp = A[k][p], akq = A[k][q];
                    A[k][p] = c * akp - s * akq;
                    A[k][q] = s * akp + c * akq;
                }
                for (int k = 0; k < 8; ++k) {   // A <- J^T * A
                    const double apk = A[p][k], aqk = A[q][k];
                    A[p][k] = c * apk - s * aqk;
                    A[q][k] = s * apk + c * aqk;
                }
                for (int k = 0; k < 8; ++k) {   // V <- V * J
                    const double vkp = V[k][p], vkq = V[k][q];
                    V[k][p] = c * vkp - s * vkq;
                    V[k][q] = s * vkp + c * vkq;
                }
            }
    }
    for (int i = 0; i < 8; ++i)
        for (int j = 0; j < 8; ++j) {
            double acc = 0.0;
            for (int k = 0; k < 8; ++k) acc += V[i][k] * V[j][k] / sqrt(A[k][k]);
            prm.W[i * 8 + j] = (float)acc;
        }

    // 1/norm_factor: norm = sqrt(5^(2a+7)/(2a+7)), a = 0..7
    for (int a = 0; a < 8; ++a)
        prm.invnorm[a] = (float)(1.0 / sqrt(pow(5.0, 2.0 * a + 7.0) / (2.0 * a + 7.0)));

    const double pi = 3.14159265358979323846;
    const double fp = 4.0 * pi;
    double yc[NM];
    yc[0]  = 0.5 * sqrt(1.0 / pi);
    yc[1]  = yc[2] = yc[3] = sqrt(3.0 / (4.0 * pi));
    yc[4]  = yc[5] = yc[7] = 0.5 * sqrt(15.0 / pi);
    yc[6]  = 0.25 * sqrt(5.0 / pi);
    yc[8]  = 0.25 * sqrt(15.0 / pi);
    yc[9]  = yc[15] = 0.25 * sqrt(35.0 / (2.0 * pi));
    yc[10] = 0.5 * sqrt(105.0 / pi);
    yc[11] = yc[13] = 0.25 * sqrt(21.0 / (2.0 * pi));
    yc[12] = 0.25 * sqrt(7.0 / pi);
    yc[14] = 0.25 * sqrt(105.0 / pi);
    yc[16] = 0.75 * sqrt(35.0 / pi);
    yc[17] = yc[23] = 0.75 * sqrt(35.0 / (2.0 * pi));
    yc[18] = 0.75 * sqrt(5.0 / pi);
    yc[19] = yc[21] = 0.75 * sqrt(5.0 / (2.0 * pi));
    yc[20] = 3.0 / 16.0 * sqrt(1.0 / pi);
    yc[22] = 3.0 / 8.0 * sqrt(5.0 / pi);
    yc[24] = 3.0 / 16.0 * sqrt(35.0 / pi);
    for (int m = 0; m < NM; ++m) prm.ycoef[m] = (float)(yc[m] * fp);

    for (int l = 0; l <= 4; ++l) prm.lscale[l] = (float)(pi * sqrt(8.0 / (2.0 * l + 1.0)));
    const float rt2 = 1.41421356237309515f;
    prm.pairf[0] = 1.f; prm.pairf[1] = rt2; prm.pairf[2] = rt2;
    prm.pairf[3] = 1.f; prm.pairf[4] = rt2; prm.pairf[5] = 1.f;

    soap_kernel<<<nsite, 256, 0, stream>>>(pos, Z, out, prm);
}

// Round 3
// 20.632 us; speedup vs baseline: 1.1798x; 1.1798x over previous
//
#include <hip/hip_runtime.h>
#include <cmath>

#define NMAX   8
#define NM     25      // (LMAX+1)^2
#define NSPEC  3
#define NPAIR  6
#define NTRIU  36
#define NATOM  512
#define NSLOT  64      // compacted-neighbor slab size (M~25 typical)
#define NOUT   1080    // NPAIR * 5 * NTRIU

struct Params {
    float W[NMAX * NMAX];   // W_ORTHO (symmetric)
    float invnorm[NMAX];    // 1 / norm_factor[alpha]
    float ycoef[NM];        // sph-harm coefficients * 4*pi
    float lscale[5];        // pi*sqrt(8/(2l+1))
    float pairf[NPAIR];     // sqrt(2) for unlike species pairs
};

__device__ const int TRIU_N[NTRIU] = {0,0,0,0,0,0,0,0, 1,1,1,1,1,1,1, 2,2,2,2,2,2,
                                      3,3,3,3,3, 4,4,4,4, 5,5,5, 6,6, 7};
__device__ const int TRIU_P[NTRIU] = {0,1,2,3,4,5,6,7, 1,2,3,4,5,6,7, 2,3,4,5,6,7,
                                      3,4,5,6,7, 4,5,6,7, 5,6,7, 6,7, 7};
__device__ const int PAIR_S1[NPAIR] = {0,0,0,1,1,2};
__device__ const int PAIR_S2[NPAIR] = {0,1,2,1,2,2};

__global__ __launch_bounds__(256)
void soap_kernel(const float* __restrict__ pos, const int* __restrict__ Z,
                 float* __restrict__ out, Params prm) {
    __shared__ int   idx_lds[NATOM];          // compacted neighbor indices
    __shared__ float g_lds[NSLOT * NMAX];
    __shared__ float y_lds[NSLOT * NM];
    __shared__ int   s_lds[NSLOT];
    __shared__ float c_lds[NSPEC * NMAX * NM];
    __shared__ int   wcnt[4], wbase[4], Mtot;

    const int tid  = threadIdx.x;
    const int lane = tid & 63;
    const int w    = tid >> 6;
    const int site = blockIdx.x;        // b*NATOM + i
    const int b    = site >> 9;         // NATOM = 512

    const float xi = pos[site * 3 + 0];
    const float yi = pos[site * 3 + 1];
    const float zi = pos[site * 3 + 2];

    if (tid == 0) Mtot = 0;
    __syncthreads();

    // ---- Phase A1: cutoff test + deterministic ballot-scan compaction ----
#pragma unroll
    for (int p = 0; p < 2; ++p) {
        const int ja = (b << 9) + p * 256 + tid;
        const float dx = xi - pos[ja * 3 + 0];
        const float dy = yi - pos[ja * 3 + 1];
        const float dz = zi - pos[ja * 3 + 2];
        const float d2 = dx * dx + dy * dy + dz * dz;
        const bool pred = d2 < 25.0f;
        const unsigned long long mask = __ballot(pred);
        if (lane == 0) wcnt[w] = __popcll(mask);
        __syncthreads();
        if (tid == 0) {
            int run = Mtot;
            for (int ww = 0; ww < 4; ++ww) { wbase[ww] = run; run += wcnt[ww]; }
            Mtot = run;
        }
        __syncthreads();
        if (pred) {
            const int slot = wbase[w] + __popcll(mask & ((1ull << lane) - 1));
            idx_lds[slot] = ja;
        }
    }
    __syncthreads();
    const int M = Mtot;

    const int  own_n = tid & 7;
    const int  own_m = tid >> 3;
    const bool owner = (tid < NMAX * NM);   // 200 threads
    float c0 = 0.f, c1 = 0.f, c2 = 0.f;

    for (int rb = 0; rb < M; rb += NSLOT) {
        const int cntr = min(NSLOT, M - rb);

        // ---- Phase A2: one thread per compacted neighbor computes Y, g, s ----
        if (tid < cntr) {
            const int ja = idx_lds[rb + tid];
            const float dx = xi - pos[ja * 3 + 0];
            const float dy = yi - pos[ja * 3 + 1];
            const float dz = zi - pos[ja * 3 + 2];
            const float d2 = dx * dx + dy * dy + dz * dz;
            const float dist = sqrtf(d2);
            const float inv  = dist > 0.f ? 1.f / dist : 0.f;
            const float x = dx * inv, y = dy * inv, z = dz * inv;
            const float x2 = x * x, y2 = y * y, z2 = z * z;
            const float r2 = x2 + y2 + z2;

            float Yv[NM];
            Yv[0]  = prm.ycoef[0];
            Yv[1]  = prm.ycoef[1]  * y;
            Yv[2]  = prm.ycoef[2]  * z;
            Yv[3]  = prm.ycoef[3]  * x;
            Yv[4]  = prm.ycoef[4]  * x * y;
            Yv[5]  = prm.ycoef[5]  * y * z;
            Yv[6]  = prm.ycoef[6]  * (3.f * z2 - r2);
            Yv[7]  = prm.ycoef[7]  * x * z;
            Yv[8]  = prm.ycoef[8]  * (x2 - y2);
            Yv[9]  = prm.ycoef[9]  * y * (3.f * x2 - y2);
            Yv[10] = prm.ycoef[10] * x * y * z;
            Yv[11] = prm.ycoef[11] * y * (5.f * z2 - r2);
            Yv[12] = prm.ycoef[12] * z * (5.f * z2 - 3.f * r2);
            Yv[13] = prm.ycoef[13] * x * (5.f * z2 - r2);
            Yv[14] = prm.ycoef[14] * z * (x2 - y2);
            Yv[15] = prm.ycoef[15] * x * (x2 - 3.f * y2);
            Yv[16] = prm.ycoef[16] * x * y * (x2 - y2);
            Yv[17] = prm.ycoef[17] * y * z * (3.f * x2 - y2);
            Yv[18] = prm.ycoef[18] * x * y * (7.f * z2 - r2);
            Yv[19] = prm.ycoef[19] * y * z * (7.f * z2 - 3.f * r2);
            Yv[20] = prm.ycoef[20] * (35.f * z2 * z2 - 30.f * z2 * r2 + 3.f * r2 * r2);
            Yv[21] = prm.ycoef[21] * x * z * (7.f * z2 - 3.f * r2);
            Yv[22] = prm.ycoef[22] * (x2 - y2) * (7.f * z2 - r2);
            Yv[23] = prm.ycoef[23] * x * z * (x2 - 3.f * y2);
            Yv[24] = prm.ycoef[24] * (x2 * x2 - 6.f * x2 * y2 + y2 * y2);
#pragma unroll
            for (int m = 0; m < NM; ++m) y_lds[tid * NM + m] = Yv[m];

            // radial basis: dr^(a+3) / norm, a = 0..7
            const float dr = 5.f - dist;
            float bas[NMAX];
            float drp = dr * dr * dr;
#pragma unroll
            for (int a = 0; a < NMAX; ++a) { bas[a] = drp * prm.invnorm[a]; drp *= dr; }
#pragma unroll
            for (int n = 0; n < NMAX; ++n) {
                float acc = 0.f;
#pragma unroll
                for (int a = 0; a < NMAX; ++a) acc += bas[a] * prm.W[n * NMAX + a];
                g_lds[tid * NMAX + n] = acc;
            }
            const int zz = Z[ja];
            s_lds[tid] = (zz == 1) ? 0 : (zz == 6) ? 1 : 2;
        }
        __syncthreads();

        // ---- Phase B: accumulate c[s][own_n][own_m] over this slab ----
        if (owner) {
            for (int sl = 0; sl < cntr; ++sl) {
                const float g  = g_lds[sl * NMAX + own_n];
                const float yv = y_lds[sl * NM + own_m];
                const int   ss = s_lds[sl];
                const float prod = g * yv;
                c0 += (ss == 0) ? prod : 0.f;
                c1 += (ss == 1) ? prod : 0.f;
                c2 += (ss == 2) ? prod : 0.f;
            }
        }
        __syncthreads();
    }

    if (owner) {
        c_lds[0 * 200 + own_n * NM + own_m] = c0;
        c_lds[1 * 200 + own_n * NM + own_m] = c1;
        c_lds[2 * 200 + own_n * NM + own_m] = c2;
    }
    __syncthreads();

    // ---- Phase C: power spectrum outputs ----
    for (int o = tid; o < NOUT; o += 256) {
        const int q   = o / 180;
        const int rem = o - q * 180;
        const int l   = rem / 36;
        const int t   = rem - l * 36;
        const int n  = TRIU_N[t], p = TRIU_P[t];
        const int s1 = PAIR_S1[q], s2 = PAIR_S2[q];
        const int m0 = l * l;
        const int mc = 2 * l + 1;
        const float* ca = &c_lds[s1 * 200 + n * NM + m0];
        const float* cb = &c_lds[s2 * 200 + p * NM + m0];
        float sum = 0.f;
        for (int k = 0; k < mc; ++k) sum += ca[k] * cb[k];
        float scale = prm.pairf[q] * prm.lscale[l];
        if (n != p) scale *= 1.41421356237309515f;
        out[site * NOUT + o] = sum * scale;
    }
}

extern "C" void kernel_launch(void* const* d_in, const int* in_sizes, int n_in,
                              void* d_out, int out_size, void* d_ws, size_t ws_size,
                              hipStream_t stream) {
    const float* pos = (const float*)d_in[0];
    const int*   Z   = (const int*)d_in[1];
    float*       out = (float*)d_out;
    const int nsite  = in_sizes[1];   // B*N = 2048

    Params prm;

    // ---- W_ORTHO = S^(-1/2) via cyclic Jacobi (double precision, host) ----
    double A[8][8], V[8][8];
    for (int i = 0; i < 8; ++i)
        for (int j = 0; j < 8; ++j) {
            const double ai = i + 1.0, aj = j + 1.0;
            A[i][j] = sqrt((5.0 + 2.0 * ai) * (5.0 + 2.0 * aj)) / (5.0 + ai + aj);
            V[i][j] = (i == j) ? 1.0 : 0.0;
        }
    for (int sweep = 0; sweep < 30; ++sweep) {
        for (int p = 0; p < 8; ++p)
            for (int q = p + 1; q < 8; ++q) {
                const double apq = A[p][q];
                if (fabs(apq) < 1e-300) continue;
                // zeroing condition for A <- J^T A J with J=[[c,s],[-s,c]]:
                // tan(2*phi) = 2*apq / (aqq - app)
                const double phi = 0.5 * atan2(2.0 * apq, A[q][q] - A[p][p]);
                const double c = cos(phi), s = sin(phi);
                for (int k = 0; k < 8; ++k) {   // A <- A * J
                    const double akp = A[k][p], akq = A[k][q];
                    A[k][p] = c * akp - s * akq;
                    A[k][q] = s * akp + c * akq;
                }
                for (int k = 0; k < 8; ++k) {   // A <- J^T * A
                    const double apk = A[p][k], aqk = A[q][k];
                    A[p][k] = c * apk - s * aqk;
                    A[q][k] = s * apk + c * aqk;
                }
                for (int k = 0; k < 8; ++k) {   // V <- V * J
                    const double vkp = V[k][p], vkq = V[k][q];
                    V[k][p] = c * vkp - s * vkq;
                    V[k][q] = s * vkp + c * vkq;
                }
            }
    }
    for (int i = 0; i < 8; ++i)
        for (int j = 0; j < 8; ++j) {
            double acc = 0.0;
            for (int k = 0; k < 8; ++k) acc += V[i][k] * V[j][k] / sqrt(A[k][k]);
            prm.W[i * 8 + j] = (float)acc;
        }

    // 1/norm_factor: norm = sqrt(5^(2a+7)/(2a+7)), a = 0..7
    for (int a = 0; a < 8; ++a)
        prm.invnorm[a] = (float)(1.0 / sqrt(pow(5.0, 2.0 * a + 7.0) / (2.0 * a + 7.0)));

    const double pi = 3.14159265358979323846;
    const double fp = 4.0 * pi;
    double yc[NM];
    yc[0]  = 0.5 * sqrt(1.0 / pi);
    yc[1]  = yc[2] = yc[3] = sqrt(3.0 / (4.0 * pi));
    yc[4]  = yc[5] = yc[7] = 0.5 * sqrt(15.0 / pi);
    yc[6]  = 0.25 * sqrt(5.0 / pi);
    yc[8]  = 0.25 * sqrt(15.0 / pi);
    yc[9]  = yc[15] = 0.25 * sqrt(35.0 / (2.0 * pi));
    yc[10] = 0.5 * sqrt(105.0 / pi);
    yc[11] = yc[13] = 0.25 * sqrt(21.0 / (2.0 * pi));
    yc[12] = 0.25 * sqrt(7.0 / pi);
    yc[14] = 0.25 * sqrt(105.0 / pi);
    yc[16] = 0.75 * sqrt(35.0 / pi);
    yc[17] = yc[23] = 0.75 * sqrt(35.0 / (2.0 * pi));
    yc[18] = 0.75 * sqrt(5.0 / pi);
    yc[19] = yc[21] = 0.75 * sqrt(5.0 / (2.0 * pi));
    yc[20] = 3.0 / 16.0 * sqrt(1.0 / pi);
    yc[22] = 3.0 / 8.0 * sqrt(5.0 / pi);
    yc[24] = 3.0 / 16.0 * sqrt(35.0 / pi);
    for (int m = 0; m < NM; ++m) prm.ycoef[m] = (float)(yc[m] * fp);

    for (int l = 0; l <= 4; ++l) prm.lscale[l] = (float)(pi * sqrt(8.0 / (2.0 * l + 1.0)));
    const float rt2 = 1.41421356237309515f;
    prm.pairf[0] = 1.f; prm.pairf[1] = rt2; prm.pairf[2] = rt2;
    prm.pairf[3] = 1.f; prm.pairf[4] = rt2; prm.pairf[5] = 1.f;

    soap_kernel<<<nsite, 256, 0, stream>>>(pos, Z, out, prm);
}